// Round 7
// baseline (1481.487 us; speedup 1.0000x reference)
//
#include <hip/hip_runtime.h>
#include <hip/hip_bf16.h>
#include <math.h>

typedef __bf16 bf16x8 __attribute__((ext_vector_type(8)));
typedef float f32x4 __attribute__((ext_vector_type(4)));

#define MFMA16(a,b,c) __builtin_amdgcn_mfma_f32_16x16x32_bf16(a,b,c,0,0,0)

constexpr int BATCH = 1024, SEQ = 80, EMB = 100, U = 512;
constexpr int KC1 = 20;   // layer-1 k-chunks of 32 (512 h + 128 emb-padded)
constexpr int KC2 = 32;   // layer-2 k-chunks of 32 (512 h2 + 512 h1)

__device__ __forceinline__ float sigf_(float x) {
  return __builtin_amdgcn_rcpf(1.f + __expf(-x));        // safe: x->-inf => rcp(inf)=0
}
__device__ __forceinline__ float tanhf_(float x) {
  return fmaf(2.f, __builtin_amdgcn_rcpf(1.f + __expf(-2.f * x)), -1.f);  // saturates, no NaN
}

// Fragment-major weight packing: out[(((lb*KC + kc)*3 + g)*64 + lane)*8 + e]
//  = W[col = g*512 + lb*16 + (lane&15)][k = kc*32 + (lane>>4)*8 + e]
//  where W: k<512 -> WH[k][col]; k-512<KXr -> WX[k-512][col]; else 0.
// Each MFMA B-fragment becomes one contiguous 1KB block -> conflict-free ds_read_b128.
__global__ void k_pack(const float* __restrict__ WH, const float* __restrict__ WX,
                       __bf16* __restrict__ out, int KC, int KXr) {
  int c = blockIdx.x * 256 + threadIdx.x;
  if (c >= 32 * KC * 3 * 64) return;
  int lane = c & 63;
  int rest = c >> 6;
  int g = rest % 3; rest /= 3;
  int kc = rest % KC;
  int lb = rest / KC;
  int ln = lane & 15, q = lane >> 4;
  int col = g * 512 + lb * 16 + ln;
  int kbase = kc * 32 + q * 8;
  bf16x8 v;
#pragma unroll
  for (int e = 0; e < 8; ++e) {
    int k = kbase + e;
    float f = 0.f;
    if (k < 512) f = WH[(size_t)k * 1536 + col];
    else if (k - 512 < KXr) f = WX[(size_t)(k - 512) * 1536 + col];
    v[e] = (__bf16)f;
  }
  *(bf16x8*)(out + (size_t)c * 8) = v;
}

__global__ void k_emb_pad(const float* __restrict__ in, __bf16* __restrict__ out) {
  int idx = blockIdx.x * 256 + threadIdx.x;
  if (idx >= 10000 * 128) return;
  int r = idx >> 7, c = idx & 127;
  out[idx] = (c < EMB) ? (__bf16)in[r * EMB + c] : (__bf16)0.f;
}

// Group-local (32-block) monotone barrier; poll = relaxed fetch_add(0) (fresh at
// coherence point, no per-poll inv). Single release/acquire agent fences.
__device__ __forceinline__ void group_bar(unsigned* cnt) {
  __syncthreads();
  if (threadIdx.x == 0) {
    __builtin_amdgcn_fence(__ATOMIC_RELEASE, "agent");
    unsigned a = __hip_atomic_fetch_add(cnt, 1u, __ATOMIC_RELAXED, __HIP_MEMORY_SCOPE_AGENT);
    unsigned target = (a / 32u + 1u) * 32u;
    while (__hip_atomic_fetch_add(cnt, 0u, __ATOMIC_RELAXED, __HIP_MEMORY_SCOPE_AGENT) < target)
      __builtin_amdgcn_s_sleep(1);
    __builtin_amdgcn_fence(__ATOMIC_ACQUIRE, "agent");
  }
  __syncthreads();
}

// Persistent fused 2-layer GRU: 8 row-groups (bid&7) x 32 unit-blocks (bid>>3).
// Block: 128 rows x 16 units, both layers (diagonal pipeline). 256 threads = 4 waves,
// each wave 32 rows (2 row-tiles) -> every B-fragment feeds 2 MFMAs.
// Weights LDS-resident in fragment-major blocks (conflict-free b128 at lane*16).
__global__ __launch_bounds__(256, 1)
void k_gru_persist(const int* __restrict__ tokens, const __bf16* __restrict__ embp,
                   const __bf16* __restrict__ wf1, const __bf16* __restrict__ wf2,
                   const float* __restrict__ b1, const float* __restrict__ b2,
                   __bf16* __restrict__ h1b0, __bf16* __restrict__ h1b1,
                   __bf16* __restrict__ h2b0, __bf16* __restrict__ h2b1,
                   const float* __restrict__ Wfc, const float* __restrict__ bfc,
                   float* __restrict__ out, unsigned* __restrict__ bar) {
  __shared__ __attribute__((aligned(16))) __bf16 wt1[KC1 * 3 * 512];  // 60 KB
  __shared__ __attribute__((aligned(16))) __bf16 wt2[KC2 * 3 * 512];  // 96 KB

  const int bid = blockIdx.x, tid = threadIdx.x;
  const int g = bid & 7, lb = bid >> 3;
  const int u0 = lb * 16, r0 = g * 128;

  // ---- stage both weight tiles (pure contiguous copy, once) ----
  {
    const bf16x8* s1 = (const bf16x8*)(wf1 + (size_t)lb * KC1 * 3 * 512);
    bf16x8* d1 = (bf16x8*)wt1;
    for (int i = tid; i < KC1 * 3 * 64; i += 256) d1[i] = s1[i];
    const bf16x8* s2 = (const bf16x8*)(wf2 + (size_t)lb * KC2 * 3 * 512);
    bf16x8* d2 = (bf16x8*)wt2;
    for (int i = tid; i < KC2 * 3 * 64; i += 256) d2[i] = s2[i];
  }
  __syncthreads();

  const int wv = tid >> 6, lane = tid & 63, ln = lane & 15, quad = lane >> 4;
  const int rw0 = r0 + wv * 32;      // this wave's 32-row tile
  const int lofs = lane * 8;         // fragment-major lane offset

  const int u = u0 + ln;
  const float bz1  = b1[u] + b1[1536 + u];
  const float br1  = b1[512 + u] + b1[1536 + 512 + u];
  const float bn1x = b1[1024 + u];
  const float bn1h = b1[1536 + 1024 + u];
  const float bz2  = b2[u] + b2[1536 + u];
  const float br2  = b2[512 + u] + b2[1536 + 512 + u];
  const float bn2x = b2[1024 + u];
  const float bn2h = b2[1536 + 1024 + u];
  const size_t wbase = ((size_t)(u >> 3) * 1024) * 8 + (u & 7);  // k-blocked h write base

  float h1st[2][4] = {{0.f,0.f,0.f,0.f},{0.f,0.f,0.f,0.f}};
  float h2st[2][4] = {{0.f,0.f,0.f,0.f},{0.f,0.f,0.f,0.f}};
  unsigned* cnt = bar + g * 64;      // 256B-spaced per-group counter

#pragma unroll 1
  for (int s = 0; s <= SEQ; ++s) {
    const __bf16* h1r = (s & 1) ? h1b0 : h1b1;
    __bf16*       h1w = (s & 1) ? h1b1 : h1b0;
    const __bf16* h2r = (s & 1) ? h2b1 : h2b0;
    __bf16*       h2w = (s & 1) ? h2b0 : h2b1;

    f32x4 z1[2], r1[2], n1h[2], n1x[2], z2[2], r2[2], n2h[2], n2x[2];
#pragma unroll
    for (int j = 0; j < 2; ++j) {
      z1[j] = r1[j] = n1h[j] = n1x[j] = (f32x4){0.f,0.f,0.f,0.f};
      z2[j] = r2[j] = n2h[j] = n2x[j] = (f32x4){0.f,0.f,0.f,0.f};
    }

    // ---- pass A: h1 A-frags feed layer-1 h-part AND layer-2 x-part (12 MFMA / 2 A / 6 B) ----
#pragma unroll 8
    for (int ks = 0; ks < 16; ++ks) {
      const __bf16* ab = h1r + ((size_t)(ks * 4 + quad) * 1024 + rw0 + ln) * 8;
      bf16x8 a0 = *(const bf16x8*)(ab);
      bf16x8 a1 = *(const bf16x8*)(ab + 128);
      bf16x8 bz_ = *(const bf16x8*)(wt1 + (ks * 3 + 0) * 512 + lofs);
      bf16x8 br_ = *(const bf16x8*)(wt1 + (ks * 3 + 1) * 512 + lofs);
      bf16x8 bn_ = *(const bf16x8*)(wt1 + (ks * 3 + 2) * 512 + lofs);
      bf16x8 cz_ = *(const bf16x8*)(wt2 + ((16 + ks) * 3 + 0) * 512 + lofs);
      bf16x8 cr_ = *(const bf16x8*)(wt2 + ((16 + ks) * 3 + 1) * 512 + lofs);
      bf16x8 cn_ = *(const bf16x8*)(wt2 + ((16 + ks) * 3 + 2) * 512 + lofs);
      z1[0]  = MFMA16(a0, bz_, z1[0]);  z1[1]  = MFMA16(a1, bz_, z1[1]);
      r1[0]  = MFMA16(a0, br_, r1[0]);  r1[1]  = MFMA16(a1, br_, r1[1]);
      n1h[0] = MFMA16(a0, bn_, n1h[0]); n1h[1] = MFMA16(a1, bn_, n1h[1]);
      z2[0]  = MFMA16(a0, cz_, z2[0]);  z2[1]  = MFMA16(a1, cz_, z2[1]);
      r2[0]  = MFMA16(a0, cr_, r2[0]);  r2[1]  = MFMA16(a1, cr_, r2[1]);
      n2x[0] = MFMA16(a0, cn_, n2x[0]); n2x[1] = MFMA16(a1, cn_, n2x[1]);
    }
    // ---- pass B: h2 recurrence (6 MFMA / 2 A / 3 B) ----
#pragma unroll 8
    for (int ks = 0; ks < 16; ++ks) {
      const __bf16* ab = h2r + ((size_t)(ks * 4 + quad) * 1024 + rw0 + ln) * 8;
      bf16x8 a0 = *(const bf16x8*)(ab);
      bf16x8 a1 = *(const bf16x8*)(ab + 128);
      bf16x8 cz_ = *(const bf16x8*)(wt2 + (ks * 3 + 0) * 512 + lofs);
      bf16x8 cr_ = *(const bf16x8*)(wt2 + (ks * 3 + 1) * 512 + lofs);
      bf16x8 cn_ = *(const bf16x8*)(wt2 + (ks * 3 + 2) * 512 + lofs);
      z2[0]  = MFMA16(a0, cz_, z2[0]);  z2[1]  = MFMA16(a1, cz_, z2[1]);
      r2[0]  = MFMA16(a0, cr_, r2[0]);  r2[1]  = MFMA16(a1, cr_, r2[1]);
      n2h[0] = MFMA16(a0, cn_, n2h[0]); n2h[1] = MFMA16(a1, cn_, n2h[1]);
    }
    // ---- pass C: embedding x-part for layer-1 ----
    {
      int se = (s < SEQ) ? s : SEQ - 1;
      int tok0 = tokens[(size_t)(rw0 + ln) * SEQ + se];
      int tok1 = tokens[(size_t)(rw0 + 16 + ln) * SEQ + se];
#pragma unroll
      for (int ks = 0; ks < 4; ++ks) {
        int k = ks * 32 + quad * 8;
        bf16x8 a0 = *(const bf16x8*)(embp + (size_t)tok0 * 128 + k);
        bf16x8 a1 = *(const bf16x8*)(embp + (size_t)tok1 * 128 + k);
        bf16x8 bz_ = *(const bf16x8*)(wt1 + ((16 + ks) * 3 + 0) * 512 + lofs);
        bf16x8 br_ = *(const bf16x8*)(wt1 + ((16 + ks) * 3 + 1) * 512 + lofs);
        bf16x8 bn_ = *(const bf16x8*)(wt1 + ((16 + ks) * 3 + 2) * 512 + lofs);
        z1[0]  = MFMA16(a0, bz_, z1[0]);  z1[1]  = MFMA16(a1, bz_, z1[1]);
        r1[0]  = MFMA16(a0, br_, r1[0]);  r1[1]  = MFMA16(a1, br_, r1[1]);
        n1x[0] = MFMA16(a0, bn_, n1x[0]); n1x[1] = MFMA16(a1, bn_, n1x[1]);
      }
    }

    // ---- gates + state update (C layout: col = ln -> unit, row = quad*4 + i) ----
    if (s < SEQ) {
#pragma unroll
      for (int rt = 0; rt < 2; ++rt)
#pragma unroll
        for (int i = 0; i < 4; ++i) {
          int row = rw0 + rt * 16 + quad * 4 + i;
          float z = sigf_(z1[rt][i] + bz1);
          float r = sigf_(r1[rt][i] + br1);
          float hh = tanhf_(n1x[rt][i] + bn1x + r * (n1h[rt][i] + bn1h));
          float hn = hh + z * (h1st[rt][i] - hh);
          h1st[rt][i] = hn;
          h1w[wbase + (size_t)row * 8] = (__bf16)hn;
        }
    }
    if (s >= 1) {
#pragma unroll
      for (int rt = 0; rt < 2; ++rt)
#pragma unroll
        for (int i = 0; i < 4; ++i) {
          int row = rw0 + rt * 16 + quad * 4 + i;
          float z = sigf_(z2[rt][i] + bz2);
          float r = sigf_(r2[rt][i] + br2);
          float hh = tanhf_(n2x[rt][i] + bn2x + r * (n2h[rt][i] + bn2h));
          float hn = hh + z * (h2st[rt][i] - hh);
          h2st[rt][i] = hn;
          h2w[wbase + (size_t)row * 8] = (__bf16)hn;
        }
    }

    group_bar(cnt);
  }

  // ---- FC epilogue: final h2 in h2b1 (k-blocked). Blocks lb<8 cover 16 rows each ----
  if (lb < 8) {
    int row = r0 + lb * 16 + wv * 4 + quad;
    float sfc = 0.f;
#pragma unroll 8
    for (int j = 0; j < 32; ++j) {
      int k = j * 16 + ln;
      sfc += (float)h2b1[((size_t)(k >> 3) * 1024 + row) * 8 + (k & 7)] * Wfc[k];
    }
    sfc += __shfl_down(sfc, 8); sfc += __shfl_down(sfc, 4);
    sfc += __shfl_down(sfc, 2); sfc += __shfl_down(sfc, 1);
    if (ln == 0) out[row] = sigf_(sfc + bfc[0]);
  }
}

extern "C" void kernel_launch(void* const* d_in, const int* in_sizes, int n_in,
                              void* d_out, int out_size, void* d_ws, size_t ws_size,
                              hipStream_t stream) {
  const int*   tokens = (const int*)d_in[0];
  const float* emb = (const float*)d_in[1];
  const float* Wx1 = (const float*)d_in[2];
  const float* Wh1 = (const float*)d_in[3];
  const float* b1  = (const float*)d_in[4];
  const float* Wx2 = (const float*)d_in[5];
  const float* Wh2 = (const float*)d_in[6];
  const float* b2  = (const float*)d_in[7];
  const float* Wfc = (const float*)d_in[8];
  const float* bfc = (const float*)d_in[9];
  float* out = (float*)d_out;

  __bf16* wf1  = (__bf16*)d_ws;                   // 32*20*3*512 = 983040 elems
  __bf16* wf2  = wf1 + 32 * KC1 * 3 * 512;        // 32*32*3*512 = 1572864 elems
  __bf16* embp = wf2 + 32 * KC2 * 3 * 512;        // [10000][128]
  __bf16* h1b0 = embp + 10000 * 128;              // bf16 states, k-blocked [64][1024][8]
  __bf16* h1b1 = h1b0 + BATCH * U;
  __bf16* h2b0 = h1b1 + BATCH * U;
  __bf16* h2b1 = h2b0 + BATCH * U;
  unsigned* bar = (unsigned*)(h2b1 + BATCH * U);  // 8 per-group counters, 256B apart

  k_pack<<<(32 * KC1 * 3 * 64 + 255) / 256, 256, 0, stream>>>(Wh1, Wx1, wf1, KC1, EMB);
  k_pack<<<(32 * KC2 * 3 * 64 + 255) / 256, 256, 0, stream>>>(Wh2, Wx2, wf2, KC2, U);
  k_emb_pad<<<(10000 * 128 + 255) / 256, 256, 0, stream>>>(emb, embp);

  // zero h state buffers (4 MB) + barrier counters
  hipMemsetAsync(h1b0, 0, (size_t)4 * BATCH * U * 2 + 2048, stream);

  void* args[] = {(void*)&tokens, (void*)&embp, (void*)&wf1, (void*)&wf2,
                  (void*)&b1, (void*)&b2, (void*)&h1b0, (void*)&h1b1,
                  (void*)&h2b0, (void*)&h2b1, (void*)&Wfc, (void*)&bfc,
                  (void*)&out, (void*)&bar};
  hipLaunchCooperativeKernel((void*)k_gru_persist, dim3(256), dim3(256), args, 0, stream);
}

// Round 8
// 867.201 us; speedup vs baseline: 1.7084x; 1.7084x over previous
//
#include <hip/hip_runtime.h>
#include <hip/hip_bf16.h>
#include <math.h>

typedef __bf16 bf16x8 __attribute__((ext_vector_type(8)));
typedef float f32x4 __attribute__((ext_vector_type(4)));

#define MFMA16(a,b,c) __builtin_amdgcn_mfma_f32_16x16x32_bf16(a,b,c,0,0,0)

constexpr int BATCH = 1024, SEQ = 80, EMB = 100, U = 512;
constexpr int KC1 = 20;   // layer-1 k-chunks of 32 (512 h + 128 emb-padded)
constexpr int KC2 = 32;   // layer-2 k-chunks of 32 (512 h2 + 512 h1)

__device__ __forceinline__ float sigf_(float x) {
  return __builtin_amdgcn_rcpf(1.f + __expf(-x));
}
__device__ __forceinline__ float tanhf_(float x) {
  return fmaf(2.f, __builtin_amdgcn_rcpf(1.f + __expf(-2.f * x)), -1.f);
}

// Fragment-major weight packing: out[(((lb*KC + kc)*3 + g)*64 + lane)*8 + e]
//  = W[col = g*512 + lb*16 + (lane&15)][k = kc*32 + (lane>>4)*8 + e]
__global__ void k_pack(const float* __restrict__ WH, const float* __restrict__ WX,
                       __bf16* __restrict__ out, int KC, int KXr) {
  int c = blockIdx.x * 256 + threadIdx.x;
  if (c >= 32 * KC * 3 * 64) return;
  int lane = c & 63;
  int rest = c >> 6;
  int g = rest % 3; rest /= 3;
  int kc = rest % KC;
  int lb = rest / KC;
  int ln = lane & 15, q = lane >> 4;
  int col = g * 512 + lb * 16 + ln;
  int kbase = kc * 32 + q * 8;
  bf16x8 v;
#pragma unroll
  for (int e = 0; e < 8; ++e) {
    int k = kbase + e;
    float f = 0.f;
    if (k < 512) f = WH[(size_t)k * 1536 + col];
    else if (k - 512 < KXr) f = WX[(size_t)(k - 512) * 1536 + col];
    v[e] = (__bf16)f;
  }
  *(bf16x8*)(out + (size_t)c * 8) = v;
}

__global__ void k_emb_pad(const float* __restrict__ in, __bf16* __restrict__ out) {
  int idx = blockIdx.x * 256 + threadIdx.x;
  if (idx >= 10000 * 128) return;
  int r = idx >> 7, c = idx & 127;
  out[idx] = (c < EMB) ? (__bf16)in[r * EMB + c] : (__bf16)0.f;
}

// LLC-fresh 32-bit load: bypass L1 (sc0) and L2 (sc1).
__device__ __forceinline__ unsigned llc_read(unsigned* p) {
  unsigned v;
  asm volatile("global_load_dword %0, %1, off sc0 sc1\n\ts_waitcnt vmcnt(0)"
               : "=v"(v) : "v"(p) : "memory");
  return v;
}

// SLOW (placement-agnostic) barrier: full agent fences, RMW poll. Known-correct.
__device__ __forceinline__ void group_bar_slow(unsigned* cnt) {
  __syncthreads();
  if (threadIdx.x == 0) {
    __builtin_amdgcn_fence(__ATOMIC_RELEASE, "agent");
    unsigned a = __hip_atomic_fetch_add(cnt, 1u, __ATOMIC_RELAXED, __HIP_MEMORY_SCOPE_AGENT);
    unsigned target = (a / 32u + 1u) * 32u;
    while (__hip_atomic_fetch_add(cnt, 0u, __ATOMIC_RELAXED, __HIP_MEMORY_SCOPE_AGENT) < target)
      __builtin_amdgcn_s_sleep(1);
    __builtin_amdgcn_fence(__ATOMIC_ACQUIRE, "agent");
  }
  __syncthreads();
}

// FAST barrier (valid only when the whole group shares one XCD): h exchange lives in
// the shared XCD L2 (plain stores, drained by the compiler's vmcnt(0) before s_barrier).
// Arrive = relaxed RMW on LLC counter; poll = sc0/sc1 load (fresh, non-serializing);
// exit = L1-only invalidate (per-CU stale lines) — L2 stays warm, nothing hits HBM.
__device__ __forceinline__ void group_bar_fast(unsigned* cnt) {
  asm volatile("s_waitcnt vmcnt(0)" ::: "memory");  // belt&braces: drain this wave's stores
  __syncthreads();
  if (threadIdx.x == 0) {
    unsigned a = __hip_atomic_fetch_add(cnt, 1u, __ATOMIC_RELAXED, __HIP_MEMORY_SCOPE_AGENT);
    unsigned target = (a / 32u + 1u) * 32u;
    while (llc_read(cnt) < target) __builtin_amdgcn_s_sleep(1);
    asm volatile("buffer_inv sc0\n\ts_waitcnt vmcnt(0)" ::: "memory");  // L1-only inv
  }
  __syncthreads();
}

// Persistent fused 2-layer GRU: 8 row-groups (bid&7) x 32 unit-blocks (bid>>3).
// Block: 128 rows x 16 units, both layers (diagonal pipeline), 4 waves x 32 rows.
// Weights LDS-resident fragment-major (conflict-free b128 at lane*16).
__global__ __launch_bounds__(256, 1)
void k_gru_persist(const int* __restrict__ tokens, const __bf16* __restrict__ embp,
                   const __bf16* __restrict__ wf1, const __bf16* __restrict__ wf2,
                   const float* __restrict__ b1, const float* __restrict__ b2,
                   __bf16* __restrict__ h1b0, __bf16* __restrict__ h1b1,
                   __bf16* __restrict__ h2b0, __bf16* __restrict__ h2b1,
                   const float* __restrict__ Wfc, const float* __restrict__ bfc,
                   float* __restrict__ out, unsigned* __restrict__ bar) {
  __shared__ __attribute__((aligned(16))) __bf16 wt1[KC1 * 3 * 512];  // 60 KB
  __shared__ __attribute__((aligned(16))) __bf16 wt2[KC2 * 3 * 512];  // 96 KB
  __shared__ int fastsh;

  const int bid = blockIdx.x, tid = threadIdx.x;
  const int g = bid & 7, lb = bid >> 3;
  const int u0 = lb * 16, r0 = g * 128;
  unsigned* cnt = bar + g * 64;        // 256B-spaced per-group counters
  unsigned* xslot = bar + 512;         // 256 per-block XCC slots

  // ---- stage both weight tiles (contiguous copy, once) ----
  {
    const bf16x8* s1 = (const bf16x8*)(wf1 + (size_t)lb * KC1 * 3 * 512);
    bf16x8* d1 = (bf16x8*)wt1;
    for (int i = tid; i < KC1 * 3 * 64; i += 256) d1[i] = s1[i];
    const bf16x8* s2 = (const bf16x8*)(wf2 + (size_t)lb * KC2 * 3 * 512);
    bf16x8* d2 = (bf16x8*)wt2;
    for (int i = tid; i < KC2 * 3 * 64; i += 256) d2[i] = s2[i];
  }

  // ---- detect whether this group is XCD-pure (fast barrier legal) ----
  {
    unsigned xcc = 0;
    asm volatile("s_getreg_b32 %0, hwreg(HW_REG_XCC_ID)" : "=s"(xcc));
    if (tid == 0)
      __hip_atomic_store(&xslot[bid], xcc + 1u, __ATOMIC_RELAXED, __HIP_MEMORY_SCOPE_AGENT);
    group_bar_slow(cnt);   // fenced: publishes slots across XCDs
    if (tid == 0) {
      unsigned x0 = __hip_atomic_load(&xslot[g], __ATOMIC_RELAXED, __HIP_MEMORY_SCOPE_AGENT);
      int f = (x0 != 0u);
      for (int i = 1; i < 32; ++i) {
        unsigned xi = __hip_atomic_load(&xslot[i * 8 + g], __ATOMIC_RELAXED, __HIP_MEMORY_SCOPE_AGENT);
        f &= (xi == x0);
      }
      fastsh = f;
    }
    __syncthreads();
  }
  const bool fastbar = (fastsh != 0);

  const int wv = tid >> 6, lane = tid & 63, ln = lane & 15, quad = lane >> 4;
  const int rw0 = r0 + wv * 32;
  const int lofs = lane * 8;

  const int u = u0 + ln;
  const float bz1  = b1[u] + b1[1536 + u];
  const float br1  = b1[512 + u] + b1[1536 + 512 + u];
  const float bn1x = b1[1024 + u];
  const float bn1h = b1[1536 + 1024 + u];
  const float bz2  = b2[u] + b2[1536 + u];
  const float br2  = b2[512 + u] + b2[1536 + 512 + u];
  const float bn2x = b2[1024 + u];
  const float bn2h = b2[1536 + 1024 + u];
  const size_t wbase = ((size_t)(u >> 3) * 1024) * 8 + (u & 7);

  float h1st[2][4] = {{0.f,0.f,0.f,0.f},{0.f,0.f,0.f,0.f}};
  float h2st[2][4] = {{0.f,0.f,0.f,0.f},{0.f,0.f,0.f,0.f}};

#pragma unroll 1
  for (int s = 0; s <= SEQ; ++s) {
    const __bf16* h1r = (s & 1) ? h1b0 : h1b1;
    __bf16*       h1w = (s & 1) ? h1b1 : h1b0;
    const __bf16* h2r = (s & 1) ? h2b1 : h2b0;
    __bf16*       h2w = (s & 1) ? h2b0 : h2b1;

    f32x4 z1[2], r1[2], n1h[2], n1x[2], z2[2], r2[2], n2h[2], n2x[2];
#pragma unroll
    for (int j = 0; j < 2; ++j) {
      z1[j] = r1[j] = n1h[j] = n1x[j] = (f32x4){0.f,0.f,0.f,0.f};
      z2[j] = r2[j] = n2h[j] = n2x[j] = (f32x4){0.f,0.f,0.f,0.f};
    }

    // ---- pass A: h1 A-frags feed layer-1 h-part AND layer-2 x-part ----
#pragma unroll 8
    for (int ks = 0; ks < 16; ++ks) {
      const __bf16* ab = h1r + ((size_t)(ks * 4 + quad) * 1024 + rw0 + ln) * 8;
      bf16x8 a0 = *(const bf16x8*)(ab);
      bf16x8 a1 = *(const bf16x8*)(ab + 128);
      bf16x8 bz_ = *(const bf16x8*)(wt1 + (ks * 3 + 0) * 512 + lofs);
      bf16x8 br_ = *(const bf16x8*)(wt1 + (ks * 3 + 1) * 512 + lofs);
      bf16x8 bn_ = *(const bf16x8*)(wt1 + (ks * 3 + 2) * 512 + lofs);
      bf16x8 cz_ = *(const bf16x8*)(wt2 + ((16 + ks) * 3 + 0) * 512 + lofs);
      bf16x8 cr_ = *(const bf16x8*)(wt2 + ((16 + ks) * 3 + 1) * 512 + lofs);
      bf16x8 cn_ = *(const bf16x8*)(wt2 + ((16 + ks) * 3 + 2) * 512 + lofs);
      z1[0]  = MFMA16(a0, bz_, z1[0]);  z1[1]  = MFMA16(a1, bz_, z1[1]);
      r1[0]  = MFMA16(a0, br_, r1[0]);  r1[1]  = MFMA16(a1, br_, r1[1]);
      n1h[0] = MFMA16(a0, bn_, n1h[0]); n1h[1] = MFMA16(a1, bn_, n1h[1]);
      z2[0]  = MFMA16(a0, cz_, z2[0]);  z2[1]  = MFMA16(a1, cz_, z2[1]);
      r2[0]  = MFMA16(a0, cr_, r2[0]);  r2[1]  = MFMA16(a1, cr_, r2[1]);
      n2x[0] = MFMA16(a0, cn_, n2x[0]); n2x[1] = MFMA16(a1, cn_, n2x[1]);
    }
    // ---- pass B: h2 recurrence ----
#pragma unroll 8
    for (int ks = 0; ks < 16; ++ks) {
      const __bf16* ab = h2r + ((size_t)(ks * 4 + quad) * 1024 + rw0 + ln) * 8;
      bf16x8 a0 = *(const bf16x8*)(ab);
      bf16x8 a1 = *(const bf16x8*)(ab + 128);
      bf16x8 cz_ = *(const bf16x8*)(wt2 + (ks * 3 + 0) * 512 + lofs);
      bf16x8 cr_ = *(const bf16x8*)(wt2 + (ks * 3 + 1) * 512 + lofs);
      bf16x8 cn_ = *(const bf16x8*)(wt2 + (ks * 3 + 2) * 512 + lofs);
      z2[0]  = MFMA16(a0, cz_, z2[0]);  z2[1]  = MFMA16(a1, cz_, z2[1]);
      r2[0]  = MFMA16(a0, cr_, r2[0]);  r2[1]  = MFMA16(a1, cr_, r2[1]);
      n2h[0] = MFMA16(a0, cn_, n2h[0]); n2h[1] = MFMA16(a1, cn_, n2h[1]);
    }
    // ---- pass C: embedding x-part for layer-1 ----
    {
      int se = (s < SEQ) ? s : SEQ - 1;
      int tok0 = tokens[(size_t)(rw0 + ln) * SEQ + se];
      int tok1 = tokens[(size_t)(rw0 + 16 + ln) * SEQ + se];
#pragma unroll
      for (int ks = 0; ks < 4; ++ks) {
        int k = ks * 32 + quad * 8;
        bf16x8 a0 = *(const bf16x8*)(embp + (size_t)tok0 * 128 + k);
        bf16x8 a1 = *(const bf16x8*)(embp + (size_t)tok1 * 128 + k);
        bf16x8 bz_ = *(const bf16x8*)(wt1 + ((16 + ks) * 3 + 0) * 512 + lofs);
        bf16x8 br_ = *(const bf16x8*)(wt1 + ((16 + ks) * 3 + 1) * 512 + lofs);
        bf16x8 bn_ = *(const bf16x8*)(wt1 + ((16 + ks) * 3 + 2) * 512 + lofs);
        z1[0]  = MFMA16(a0, bz_, z1[0]);  z1[1]  = MFMA16(a1, bz_, z1[1]);
        r1[0]  = MFMA16(a0, br_, r1[0]);  r1[1]  = MFMA16(a1, br_, r1[1]);
        n1x[0] = MFMA16(a0, bn_, n1x[0]); n1x[1] = MFMA16(a1, bn_, n1x[1]);
      }
    }

    // ---- gates + state update (C layout: col = ln -> unit, row = quad*4 + i) ----
    if (s < SEQ) {
#pragma unroll
      for (int rt = 0; rt < 2; ++rt)
#pragma unroll
        for (int i = 0; i < 4; ++i) {
          int row = rw0 + rt * 16 + quad * 4 + i;
          float z = sigf_(z1[rt][i] + bz1);
          float r = sigf_(r1[rt][i] + br1);
          float hh = tanhf_(n1x[rt][i] + bn1x + r * (n1h[rt][i] + bn1h));
          float hn = hh + z * (h1st[rt][i] - hh);
          h1st[rt][i] = hn;
          h1w[wbase + (size_t)row * 8] = (__bf16)hn;
        }
    }
    if (s >= 1) {
#pragma unroll
      for (int rt = 0; rt < 2; ++rt)
#pragma unroll
        for (int i = 0; i < 4; ++i) {
          int row = rw0 + rt * 16 + quad * 4 + i;
          float z = sigf_(z2[rt][i] + bz2);
          float r = sigf_(r2[rt][i] + br2);
          float hh = tanhf_(n2x[rt][i] + bn2x + r * (n2h[rt][i] + bn2h));
          float hn = hh + z * (h2st[rt][i] - hh);
          h2st[rt][i] = hn;
          h2w[wbase + (size_t)row * 8] = (__bf16)hn;
        }
    }

    if (fastbar) group_bar_fast(cnt);
    else         group_bar_slow(cnt);
  }

  // ---- FC epilogue: final h2 in h2b1 (k-blocked). Blocks lb<8 cover 16 rows each ----
  if (lb < 8) {
    int row = r0 + lb * 16 + wv * 4 + quad;
    float sfc = 0.f;
#pragma unroll 8
    for (int j = 0; j < 32; ++j) {
      int k = j * 16 + ln;
      sfc += (float)h2b1[((size_t)(k >> 3) * 1024 + row) * 8 + (k & 7)] * Wfc[k];
    }
    sfc += __shfl_down(sfc, 8); sfc += __shfl_down(sfc, 4);
    sfc += __shfl_down(sfc, 2); sfc += __shfl_down(sfc, 1);
    if (ln == 0) out[row] = sigf_(sfc + bfc[0]);
  }
}

extern "C" void kernel_launch(void* const* d_in, const int* in_sizes, int n_in,
                              void* d_out, int out_size, void* d_ws, size_t ws_size,
                              hipStream_t stream) {
  const int*   tokens = (const int*)d_in[0];
  const float* emb = (const float*)d_in[1];
  const float* Wx1 = (const float*)d_in[2];
  const float* Wh1 = (const float*)d_in[3];
  const float* b1  = (const float*)d_in[4];
  const float* Wx2 = (const float*)d_in[5];
  const float* Wh2 = (const float*)d_in[6];
  const float* b2  = (const float*)d_in[7];
  const float* Wfc = (const float*)d_in[8];
  const float* bfc = (const float*)d_in[9];
  float* out = (float*)d_out;

  __bf16* wf1  = (__bf16*)d_ws;                   // 32*20*3*512
  __bf16* wf2  = wf1 + 32 * KC1 * 3 * 512;        // 32*32*3*512
  __bf16* embp = wf2 + 32 * KC2 * 3 * 512;        // [10000][128]
  __bf16* h1b0 = embp + 10000 * 128;              // bf16 states, k-blocked [64][1024][8]
  __bf16* h1b1 = h1b0 + BATCH * U;
  __bf16* h2b0 = h1b1 + BATCH * U;
  __bf16* h2b1 = h2b0 + BATCH * U;
  unsigned* bar = (unsigned*)(h2b1 + BATCH * U);  // [0..512): 8 counters; [512..768): xcc slots

  k_pack<<<(32 * KC1 * 3 * 64 + 255) / 256, 256, 0, stream>>>(Wh1, Wx1, wf1, KC1, EMB);
  k_pack<<<(32 * KC2 * 3 * 64 + 255) / 256, 256, 0, stream>>>(Wh2, Wx2, wf2, KC2, U);
  k_emb_pad<<<(10000 * 128 + 255) / 256, 256, 0, stream>>>(emb, embp);

  // zero h state buffers (4 MB) + barrier counters (xcc slots are write-before-read)
  hipMemsetAsync(h1b0, 0, (size_t)4 * BATCH * U * 2 + 2048, stream);

  void* args[] = {(void*)&tokens, (void*)&embp, (void*)&wf1, (void*)&wf2,
                  (void*)&b1, (void*)&b2, (void*)&h1b0, (void*)&h1b1,
                  (void*)&h2b0, (void*)&h2b1, (void*)&Wfc, (void*)&bfc,
                  (void*)&out, (void*)&bar};
  hipLaunchCooperativeKernel((void*)k_gru_persist, dim3(256), dim3(256), args, 0, stream);
}

// Round 9
// 728.792 us; speedup vs baseline: 2.0328x; 1.1899x over previous
//
#include <hip/hip_runtime.h>
#include <hip/hip_bf16.h>
#include <math.h>

typedef __bf16 bf16x8 __attribute__((ext_vector_type(8)));
typedef float f32x4 __attribute__((ext_vector_type(4)));

#define MFMA16(a,b,c) __builtin_amdgcn_mfma_f32_16x16x32_bf16(a,b,c,0,0,0)

constexpr int BATCH = 1024, SEQ = 80, EMB = 100, U = 512;
constexpr int KC1 = 20;   // layer-1 k-chunks of 32 (512 h + 128 emb-padded)
constexpr int KC2 = 32;   // layer-2 k-chunks of 32 (512 h2 + 512 h1)

__device__ __forceinline__ float sigf_(float x) {
  return __builtin_amdgcn_rcpf(1.f + __expf(-x));
}
__device__ __forceinline__ float tanhf_(float x) {
  return fmaf(2.f, __builtin_amdgcn_rcpf(1.f + __expf(-2.f * x)), -1.f);
}

// Fragment-major weight packing: out[(((lb*KC + kc)*3 + g)*64 + lane)*8 + e]
//  = W[col = g*512 + lb*16 + (lane&15)][k = kc*32 + (lane>>4)*8 + e]
__global__ void k_pack(const float* __restrict__ WH, const float* __restrict__ WX,
                       __bf16* __restrict__ out, int KC, int KXr) {
  int c = blockIdx.x * 256 + threadIdx.x;
  if (c >= 32 * KC * 3 * 64) return;
  int lane = c & 63;
  int rest = c >> 6;
  int g = rest % 3; rest /= 3;
  int kc = rest % KC;
  int lb = rest / KC;
  int ln = lane & 15, q = lane >> 4;
  int col = g * 512 + lb * 16 + ln;
  int kbase = kc * 32 + q * 8;
  bf16x8 v;
#pragma unroll
  for (int e = 0; e < 8; ++e) {
    int k = kbase + e;
    float f = 0.f;
    if (k < 512) f = WH[(size_t)k * 1536 + col];
    else if (k - 512 < KXr) f = WX[(size_t)(k - 512) * 1536 + col];
    v[e] = (__bf16)f;
  }
  *(bf16x8*)(out + (size_t)c * 8) = v;
}

__global__ void k_emb_pad(const float* __restrict__ in, __bf16* __restrict__ out) {
  int idx = blockIdx.x * 256 + threadIdx.x;
  if (idx >= 10000 * 128) return;
  int r = idx >> 7, c = idx & 127;
  out[idx] = (c < EMB) ? (__bf16)in[r * EMB + c] : (__bf16)0.f;
}

// LLC-fresh 32-bit load: bypass L1 (sc0) and L2 (sc1).
__device__ __forceinline__ unsigned llc_read(unsigned* p) {
  unsigned v;
  asm volatile("global_load_dword %0, %1, off sc0 sc1\n\ts_waitcnt vmcnt(0)"
               : "=v"(v) : "v"(p) : "memory");
  return v;
}

// SLOW (placement-agnostic) barrier: full agent fences, RMW poll. Known-correct.
__device__ __forceinline__ void group_bar_slow(unsigned* cnt) {
  __syncthreads();
  if (threadIdx.x == 0) {
    __builtin_amdgcn_fence(__ATOMIC_RELEASE, "agent");
    unsigned a = __hip_atomic_fetch_add(cnt, 1u, __ATOMIC_RELAXED, __HIP_MEMORY_SCOPE_AGENT);
    unsigned target = (a / 32u + 1u) * 32u;
    while (__hip_atomic_fetch_add(cnt, 0u, __ATOMIC_RELAXED, __HIP_MEMORY_SCOPE_AGENT) < target)
      __builtin_amdgcn_s_sleep(1);
    __builtin_amdgcn_fence(__ATOMIC_ACQUIRE, "agent");
  }
  __syncthreads();
}

// FAST barrier (group XCD-pure): h exchange stays in the shared XCD L2; arrive =
// relaxed RMW on LLC counter; poll = sc0/sc1 load; exit = L1-only invalidate.
__device__ __forceinline__ void group_bar_fast(unsigned* cnt) {
  asm volatile("s_waitcnt vmcnt(0)" ::: "memory");
  __syncthreads();
  if (threadIdx.x == 0) {
    unsigned a = __hip_atomic_fetch_add(cnt, 1u, __ATOMIC_RELAXED, __HIP_MEMORY_SCOPE_AGENT);
    unsigned target = (a / 32u + 1u) * 32u;
    while (llc_read(cnt) < target) __builtin_amdgcn_s_sleep(1);
    asm volatile("buffer_inv sc0\n\ts_waitcnt vmcnt(0)" ::: "memory");
  }
  __syncthreads();
}

// Persistent fused 2-layer GRU: 8 row-groups (bid&7) x 32 unit-blocks (bid>>3).
// Block: 128 rows x 16 units, both layers (diagonal pipeline).
// 512 threads = 8 waves x 16 rows -> 2 waves/SIMD so LDS/MFMA/VALU/TA pipes overlap.
__global__ __launch_bounds__(512, 2)
void k_gru_persist(const int* __restrict__ tokens, const __bf16* __restrict__ embp,
                   const __bf16* __restrict__ wf1, const __bf16* __restrict__ wf2,
                   const float* __restrict__ b1, const float* __restrict__ b2,
                   __bf16* __restrict__ h1b0, __bf16* __restrict__ h1b1,
                   __bf16* __restrict__ h2b0, __bf16* __restrict__ h2b1,
                   const float* __restrict__ Wfc, const float* __restrict__ bfc,
                   float* __restrict__ out, unsigned* __restrict__ bar) {
  __shared__ __attribute__((aligned(16))) __bf16 wt1[KC1 * 3 * 512];  // 60 KB
  __shared__ __attribute__((aligned(16))) __bf16 wt2[KC2 * 3 * 512];  // 96 KB
  __shared__ int fastsh;

  const int bid = blockIdx.x, tid = threadIdx.x;
  const int g = bid & 7, lb = bid >> 3;
  const int u0 = lb * 16, r0 = g * 128;
  unsigned* cnt = bar + g * 64;        // 256B-spaced per-group counters
  unsigned* xslot = bar + 512;         // 256 per-block XCC slots

  // ---- stage both weight tiles (contiguous copy, once) ----
  {
    const bf16x8* s1 = (const bf16x8*)(wf1 + (size_t)lb * KC1 * 3 * 512);
    bf16x8* d1 = (bf16x8*)wt1;
    for (int i = tid; i < KC1 * 3 * 64; i += 512) d1[i] = s1[i];
    const bf16x8* s2 = (const bf16x8*)(wf2 + (size_t)lb * KC2 * 3 * 512);
    bf16x8* d2 = (bf16x8*)wt2;
    for (int i = tid; i < KC2 * 3 * 64; i += 512) d2[i] = s2[i];
  }

  // ---- detect whether this group is XCD-pure (fast barrier legal) ----
  {
    unsigned xcc = 0;
    asm volatile("s_getreg_b32 %0, hwreg(HW_REG_XCC_ID)" : "=s"(xcc));
    if (tid == 0)
      __hip_atomic_store(&xslot[bid], xcc + 1u, __ATOMIC_RELAXED, __HIP_MEMORY_SCOPE_AGENT);
    group_bar_slow(cnt);   // fenced: publishes slots across XCDs
    if (tid == 0) {
      unsigned x0 = __hip_atomic_load(&xslot[g], __ATOMIC_RELAXED, __HIP_MEMORY_SCOPE_AGENT);
      int f = (x0 != 0u);
      for (int i = 1; i < 32; ++i) {
        unsigned xi = __hip_atomic_load(&xslot[i * 8 + g], __ATOMIC_RELAXED, __HIP_MEMORY_SCOPE_AGENT);
        f &= (xi == x0);
      }
      fastsh = f;
    }
    __syncthreads();
  }
  const bool fastbar = (fastsh != 0);

  const int wv = tid >> 6, lane = tid & 63, ln = lane & 15, quad = lane >> 4;
  const int rw0 = r0 + wv * 16;        // this wave's 16-row tile
  const int lofs = lane * 8;           // fragment-major lane offset

  const int u = u0 + ln;
  const float bz1  = b1[u] + b1[1536 + u];
  const float br1  = b1[512 + u] + b1[1536 + 512 + u];
  const float bn1x = b1[1024 + u];
  const float bn1h = b1[1536 + 1024 + u];
  const float bz2  = b2[u] + b2[1536 + u];
  const float br2  = b2[512 + u] + b2[1536 + 512 + u];
  const float bn2x = b2[1024 + u];
  const float bn2h = b2[1536 + 1024 + u];
  const size_t wbase = ((size_t)(u >> 3) * 1024) * 8 + (u & 7);

  float h1st[4] = {0.f, 0.f, 0.f, 0.f};
  float h2st[4] = {0.f, 0.f, 0.f, 0.f};

#pragma unroll 1
  for (int s = 0; s <= SEQ; ++s) {
    const __bf16* h1r = (s & 1) ? h1b0 : h1b1;
    __bf16*       h1w = (s & 1) ? h1b1 : h1b0;
    const __bf16* h2r = (s & 1) ? h2b1 : h2b0;
    __bf16*       h2w = (s & 1) ? h2b0 : h2b1;

    f32x4 z1, r1, n1h, n1x, z2, r2, n2h, n2x;
    z1 = r1 = n1h = n1x = z2 = r2 = n2h = n2x = (f32x4){0.f, 0.f, 0.f, 0.f};

    // ---- pass A: h1 A-frag feeds layer-1 h-part AND layer-2 x-part (1 A / 6 B / 6 MFMA) ----
#pragma unroll 8
    for (int ks = 0; ks < 16; ++ks) {
      bf16x8 a = *(const bf16x8*)(h1r + ((size_t)(ks * 4 + quad) * 1024 + rw0 + ln) * 8);
      z1  = MFMA16(a, *(const bf16x8*)(wt1 + (ks * 3 + 0) * 512 + lofs), z1);
      r1  = MFMA16(a, *(const bf16x8*)(wt1 + (ks * 3 + 1) * 512 + lofs), r1);
      n1h = MFMA16(a, *(const bf16x8*)(wt1 + (ks * 3 + 2) * 512 + lofs), n1h);
      z2  = MFMA16(a, *(const bf16x8*)(wt2 + ((16 + ks) * 3 + 0) * 512 + lofs), z2);
      r2  = MFMA16(a, *(const bf16x8*)(wt2 + ((16 + ks) * 3 + 1) * 512 + lofs), r2);
      n2x = MFMA16(a, *(const bf16x8*)(wt2 + ((16 + ks) * 3 + 2) * 512 + lofs), n2x);
    }
    // ---- pass B: h2 recurrence (1 A / 3 B / 3 MFMA) ----
#pragma unroll 8
    for (int ks = 0; ks < 16; ++ks) {
      bf16x8 a = *(const bf16x8*)(h2r + ((size_t)(ks * 4 + quad) * 1024 + rw0 + ln) * 8);
      z2  = MFMA16(a, *(const bf16x8*)(wt2 + (ks * 3 + 0) * 512 + lofs), z2);
      r2  = MFMA16(a, *(const bf16x8*)(wt2 + (ks * 3 + 1) * 512 + lofs), r2);
      n2h = MFMA16(a, *(const bf16x8*)(wt2 + (ks * 3 + 2) * 512 + lofs), n2h);
    }
    // ---- pass C: embedding x-part for layer-1 ----
    {
      int se = (s < SEQ) ? s : SEQ - 1;
      int tok = tokens[(size_t)(rw0 + ln) * SEQ + se];
#pragma unroll
      for (int ks = 0; ks < 4; ++ks) {
        bf16x8 a = *(const bf16x8*)(embp + (size_t)tok * 128 + ks * 32 + quad * 8);
        z1  = MFMA16(a, *(const bf16x8*)(wt1 + ((16 + ks) * 3 + 0) * 512 + lofs), z1);
        r1  = MFMA16(a, *(const bf16x8*)(wt1 + ((16 + ks) * 3 + 1) * 512 + lofs), r1);
        n1x = MFMA16(a, *(const bf16x8*)(wt1 + ((16 + ks) * 3 + 2) * 512 + lofs), n1x);
      }
    }

    // ---- gates + state update (C layout: col = ln -> unit, row = quad*4 + i) ----
    if (s < SEQ) {
#pragma unroll
      for (int i = 0; i < 4; ++i) {
        int row = rw0 + quad * 4 + i;
        float z = sigf_(z1[i] + bz1);
        float r = sigf_(r1[i] + br1);
        float hh = tanhf_(n1x[i] + bn1x + r * (n1h[i] + bn1h));
        float hn = hh + z * (h1st[i] - hh);
        h1st[i] = hn;
        h1w[wbase + (size_t)row * 8] = (__bf16)hn;
      }
    }
    if (s >= 1) {
#pragma unroll
      for (int i = 0; i < 4; ++i) {
        int row = rw0 + quad * 4 + i;
        float z = sigf_(z2[i] + bz2);
        float r = sigf_(r2[i] + br2);
        float hh = tanhf_(n2x[i] + bn2x + r * (n2h[i] + bn2h));
        float hn = hh + z * (h2st[i] - hh);
        h2st[i] = hn;
        h2w[wbase + (size_t)row * 8] = (__bf16)hn;
      }
    }

    if (fastbar) group_bar_fast(cnt);
    else         group_bar_slow(cnt);
  }

  // ---- FC epilogue: final h2 in h2b1 (k-blocked). Blocks lb<8 cover 16 rows each ----
  if (lb < 8) {
    int row = r0 + lb * 16 + wv * 2 + (lane >> 5);
    int l32 = lane & 31;
    float sfc = 0.f;
#pragma unroll
    for (int k = l32; k < U; k += 32)
      sfc += (float)h2b1[((size_t)(k >> 3) * 1024 + row) * 8 + (k & 7)] * Wfc[k];
#pragma unroll
    for (int off = 16; off; off >>= 1) sfc += __shfl_down(sfc, off, 32);
    if (l32 == 0) out[row] = sigf_(sfc + bfc[0]);
  }
}

extern "C" void kernel_launch(void* const* d_in, const int* in_sizes, int n_in,
                              void* d_out, int out_size, void* d_ws, size_t ws_size,
                              hipStream_t stream) {
  const int*   tokens = (const int*)d_in[0];
  const float* emb = (const float*)d_in[1];
  const float* Wx1 = (const float*)d_in[2];
  const float* Wh1 = (const float*)d_in[3];
  const float* b1  = (const float*)d_in[4];
  const float* Wx2 = (const float*)d_in[5];
  const float* Wh2 = (const float*)d_in[6];
  const float* b2  = (const float*)d_in[7];
  const float* Wfc = (const float*)d_in[8];
  const float* bfc = (const float*)d_in[9];
  float* out = (float*)d_out;

  __bf16* wf1  = (__bf16*)d_ws;                   // 32*20*3*512
  __bf16* wf2  = wf1 + 32 * KC1 * 3 * 512;        // 32*32*3*512
  __bf16* embp = wf2 + 32 * KC2 * 3 * 512;        // [10000][128]
  __bf16* h1b0 = embp + 10000 * 128;              // bf16 states, k-blocked [64][1024][8]
  __bf16* h1b1 = h1b0 + BATCH * U;
  __bf16* h2b0 = h1b1 + BATCH * U;
  __bf16* h2b1 = h2b0 + BATCH * U;
  unsigned* bar = (unsigned*)(h2b1 + BATCH * U);  // [0..512): 8 counters; [512..768): xcc slots

  k_pack<<<(32 * KC1 * 3 * 64 + 255) / 256, 256, 0, stream>>>(Wh1, Wx1, wf1, KC1, EMB);
  k_pack<<<(32 * KC2 * 3 * 64 + 255) / 256, 256, 0, stream>>>(Wh2, Wx2, wf2, KC2, U);
  k_emb_pad<<<(10000 * 128 + 255) / 256, 256, 0, stream>>>(emb, embp);

  // zero h state buffers (4 MB) + barrier counters (xcc slots are write-before-read)
  hipMemsetAsync(h1b0, 0, (size_t)4 * BATCH * U * 2 + 2048, stream);

  void* args[] = {(void*)&tokens, (void*)&embp, (void*)&wf1, (void*)&wf2,
                  (void*)&b1, (void*)&b2, (void*)&h1b0, (void*)&h1b1,
                  (void*)&h2b0, (void*)&h2b1, (void*)&Wfc, (void*)&bfc,
                  (void*)&out, (void*)&bar};
  hipLaunchCooperativeKernel((void*)k_gru_persist, dim3(256), dim3(512), args, 0, stream);
}